// Round 1
// baseline (745.869 us; speedup 1.0000x reference)
//
#include <hip/hip_runtime.h>
#include <math.h>

#define D_MODEL 2048
#define NEXP 64
#define TOKENS 32768
#define BM 64
#define BK 32
#define NT 256
#define XST (BK + 4)     // 36-float row stride: bank-quad offset 4 per row
#define LST (NEXP + 1)   // 65

__global__ __launch_bounds__(NT, 2)
void router_kernel(const float* __restrict__ x, const float* __restrict__ W,
                   float* __restrict__ out)
{
    __shared__ float xs[2][BM][XST];
    __shared__ float ws[2][NEXP][XST];
    __shared__ float logits[BM][LST];

    const int tid  = threadIdx.x;
    const int row0 = blockIdx.x * BM;
    const int tg   = tid >> 4;   // 0..15 token group; within a wave: 4 consecutive values
    const int tc   = tid & 15;   // 0..15 expert group

    float acc[4][4];
#pragma unroll
    for (int i = 0; i < 4; ++i)
#pragma unroll
        for (int j = 0; j < 4; ++j) acc[i][j] = 0.f;

    // Staging: x tile BM*BK = 2048 floats = 512 float4 -> 2/thread; same for W.
    const int f0  = tid;
    const int f1  = 256 + tid;
    const int t0s = f0 >> 3, k0s = (f0 & 7) * 4;
    const int t1s = f1 >> 3, k1s = (f1 & 7) * 4;

    float4 rx0, rx1, rw0, rw1;

    auto stage_load = [&](int c) {
        const int k0 = c * BK;
        rx0 = *(const float4*)&x[(size_t)(row0 + t0s) * D_MODEL + k0 + k0s];
        rx1 = *(const float4*)&x[(size_t)(row0 + t1s) * D_MODEL + k0 + k1s];
        rw0 = *(const float4*)&W[(size_t)t0s * D_MODEL + k0 + k0s];
        rw1 = *(const float4*)&W[(size_t)t1s * D_MODEL + k0 + k1s];
    };
    auto stage_write = [&](int b) {
        *(float4*)&xs[b][t0s][k0s] = rx0;
        *(float4*)&xs[b][t1s][k1s] = rx1;
        *(float4*)&ws[b][t0s][k0s] = rw0;
        *(float4*)&ws[b][t1s][k1s] = rw1;
    };

    stage_load(0);
    stage_write(0);
    __syncthreads();

    const int nk = D_MODEL / BK;  // 64
    for (int c = 0; c < nk; ++c) {
        const int cur = c & 1;
        if (c + 1 < nk) stage_load(c + 1);   // issue early: HBM latency hides under compute
#pragma unroll
        for (int kk = 0; kk < BK; kk += 4) {
            float4 a[4], b[4];
#pragma unroll
            for (int i = 0; i < 4; ++i)
                a[i] = *(const float4*)&xs[cur][tg + 16 * i][kk];
#pragma unroll
            for (int j = 0; j < 4; ++j)
                b[j] = *(const float4*)&ws[cur][tc + 16 * j][kk];
#pragma unroll
            for (int i = 0; i < 4; ++i)
#pragma unroll
                for (int j = 0; j < 4; ++j) {
                    acc[i][j] = fmaf(a[i].x, b[j].x, acc[i][j]);
                    acc[i][j] = fmaf(a[i].y, b[j].y, acc[i][j]);
                    acc[i][j] = fmaf(a[i].z, b[j].z, acc[i][j]);
                    acc[i][j] = fmaf(a[i].w, b[j].w, acc[i][j]);
                }
        }
        if (c + 1 < nk) stage_write((c + 1) & 1);  // waitcnt+write after compute
        __syncthreads();
    }

    // Dump logits to LDS for the per-token top-2 scan.
#pragma unroll
    for (int i = 0; i < 4; ++i)
#pragma unroll
        for (int j = 0; j < 4; ++j)
            logits[tg + 16 * i][tc + 16 * j] = acc[i][j];
    __syncthreads();

    if (tid < BM) {
        const int t = tid;
        float m1 = -INFINITY, m2 = -INFINITY;
        int i1 = 0, i2 = 0;
#pragma unroll
        for (int e = 0; e < NEXP; ++e) {
            float v = logits[t][e];
            if (v > m1)      { m2 = m1; i2 = i1; m1 = v; i1 = e; }  // strict >: ties keep lower index (matches jax.lax.top_k)
            else if (v > m2) { m2 = v; i2 = e; }
        }
        // gates = softmax over {m1,m2}: exact renormalized top-2 of full softmax
        float ex = expf(m2 - m1);          // <= 1
        float g1 = 1.0f / (1.0f + ex);
        float g2 = ex * g1;
        const int row = row0 + t;
        out[(size_t)row * 2 + 0] = g1;
        out[(size_t)row * 2 + 1] = g2;
        out[(size_t)TOKENS * 2 + (size_t)row * 2 + 0] = (float)i1;
        out[(size_t)TOKENS * 2 + (size_t)row * 2 + 1] = (float)i2;
    }
}

extern "C" void kernel_launch(void* const* d_in, const int* in_sizes, int n_in,
                              void* d_out, int out_size, void* d_ws, size_t ws_size,
                              hipStream_t stream) {
    const float* x = (const float*)d_in[0];
    const float* W = (const float*)d_in[1];
    float* out = (float*)d_out;
    router_kernel<<<TOKENS / BM, NT, 0, stream>>>(x, W, out);
}

// Round 2
// 152.796 us; speedup vs baseline: 4.8815x; 4.8815x over previous
//
#include <hip/hip_runtime.h>
#include <math.h>
#include <stdint.h>

#define D_MODEL 2048
#define NEXP    64
#define TOKENS  32768
#define BM      64
#define BK      64
#define NT      256
#define NCHUNK  (D_MODEL / BK)   // 32

typedef __attribute__((address_space(3))) uint32_t       lds_u32_t;
typedef const __attribute__((address_space(1))) uint32_t gbl_u32_t;

// Stage one BK-chunk (64x64 floats each of x-tile and W-tile) into LDS buffer b.
// Each wave issues 4+4 global_load_lds packets of 1024B (4 rows x 64 floats).
// Global source is pre-swizzled (slot ^ (row&7)) so the linear LDS image is
// bank-swizzled; readers undo the XOR. (both-sides-or-neither, m173/m201.)
#define STAGE(c, b)                                                           \
    _Pragma("unroll")                                                         \
    for (int g = 0; g < 4; ++g) {                                             \
        const int G_ = 4 * wave + g;                                          \
        __builtin_amdgcn_global_load_lds((gbl_u32_t*)(xsrc[g] + (c) * BK),    \
                                         (lds_u32_t*)&xs[b][4 * G_][0], 16, 0, 0); \
        __builtin_amdgcn_global_load_lds((gbl_u32_t*)(wsrc[g] + (c) * BK),    \
                                         (lds_u32_t*)&ws[b][4 * G_][0], 16, 0, 0); \
    }

__global__ __launch_bounds__(NT, 2)
void router_kernel(const float* __restrict__ x, const float* __restrict__ W,
                   float* __restrict__ out)
{
    __shared__ float xs[2][BM][BK];    // 32 KB, token rows
    __shared__ float ws[2][NEXP][BK];  // 32 KB, expert rows

    const int tid  = threadIdx.x;
    const int lane = tid & 63;
    const int wave = tid >> 6;          // 0..3 (wave-uniform)
    const int row0 = blockIdx.x * BM;

    const int ec = tid & 15;            // expert group: experts ec+16j
    const int tr = tid >> 4;            // token  group: tokens  tr+16i

    // ---- staging: per-lane pre-swizzled global sources ----
    const int lrow  = lane >> 4;        // row within 1024B packet (0..3)
    const int lslot = lane & 15;        // float4 slot within row
    const float* xsrc[4];
    const float* wsrc[4];
#pragma unroll
    for (int g = 0; g < 4; ++g) {
        const int r   = 16 * wave + 4 * g + lrow;   // 0..63
        const int col = 4 * (lslot ^ (r & 7));      // pre-swizzled source col
        xsrc[g] = x + (size_t)(row0 + r) * D_MODEL + col;
        wsrc[g] = W + (size_t)r * D_MODEL + col;
    }

    float acc[4][4];
#pragma unroll
    for (int i = 0; i < 4; ++i)
#pragma unroll
        for (int j = 0; j < 4; ++j) acc[i][j] = 0.f;

    STAGE(0, 0);
    __syncthreads();

    const int trs = tr & 7;   // swizzle key for a-reads (row&7 of all my rows)
    const int ecs = ec & 7;   // swizzle key for b-reads

    for (int c = 0; c < NCHUNK; ++c) {
        const int buf = c & 1;
        if (c + 1 < NCHUNK) { STAGE(c + 1, buf ^ 1); }
#pragma unroll
        for (int q = 0; q < BK / 4; ++q) {
            const int sA = 4 * (q ^ trs);   // un-swizzle: slot holds quad slot^(r&7)
            const int sB = 4 * (q ^ ecs);
            float4 a[4], b[4];
#pragma unroll
            for (int i = 0; i < 4; ++i)
                a[i] = *(const float4*)&xs[buf][tr + 16 * i][sA];
#pragma unroll
            for (int j = 0; j < 4; ++j)
                b[j] = *(const float4*)&ws[buf][ec + 16 * j][sB];
#pragma unroll
            for (int i = 0; i < 4; ++i)
#pragma unroll
                for (int j = 0; j < 4; ++j) {
                    acc[i][j] = fmaf(a[i].x, b[j].x, acc[i][j]);
                    acc[i][j] = fmaf(a[i].y, b[j].y, acc[i][j]);
                    acc[i][j] = fmaf(a[i].z, b[j].z, acc[i][j]);
                    acc[i][j] = fmaf(a[i].w, b[j].w, acc[i][j]);
                }
        }
        __syncthreads();   // compiler emits vmcnt(0) drain: next buffer ready
    }

    // ---- epilogue: logits -> top-2 -> gates/indices ----
    // Transposed [expert][token] layout aliased onto the (dead) xs buffer:
    // scan reads are then fully coalesced across lanes (conflict-free).
    float* logits = &xs[0][0][0];   // 64*64 floats = exactly xs[0]
#pragma unroll
    for (int i = 0; i < 4; ++i)
#pragma unroll
        for (int j = 0; j < 4; ++j)
            logits[(ec + 16 * j) * BM + (tr + 16 * i)] = acc[i][j];
    __syncthreads();

    if (tid < BM) {
        const int t = tid;
        float m1 = -INFINITY, m2 = -INFINITY;
        int i1 = 0, i2 = 0;
#pragma unroll 8
        for (int e = 0; e < NEXP; ++e) {
            float v = logits[e * BM + t];
            if (v > m1)      { m2 = m1; i2 = i1; m1 = v; i1 = e; }  // strict >: lowest index wins ties (jax.lax.top_k)
            else if (v > m2) { m2 = v; i2 = e; }
        }
        // renormalized top-2 softmax == softmax over {m1,m2}
        float ex = expf(m2 - m1);     // <= 1
        float g1 = 1.0f / (1.0f + ex);
        float g2 = ex * g1;
        const int row = row0 + t;
        out[(size_t)row * 2 + 0] = g1;
        out[(size_t)row * 2 + 1] = g2;
        out[(size_t)TOKENS * 2 + (size_t)row * 2 + 0] = (float)i1;
        out[(size_t)TOKENS * 2 + (size_t)row * 2 + 1] = (float)i2;
    }
}

extern "C" void kernel_launch(void* const* d_in, const int* in_sizes, int n_in,
                              void* d_out, int out_size, void* d_ws, size_t ws_size,
                              hipStream_t stream) {
    const float* x = (const float*)d_in[0];
    const float* W = (const float*)d_in[1];
    float* out = (float*)d_out;
    router_kernel<<<TOKENS / BM, NT, 0, stream>>>(x, W, out);
}